// Round 14
// baseline (480.735 us; speedup 1.0000x reference)
//
#include <hip/hip_runtime.h>
#include <math.h>

// ===================== constants =====================
static constexpr int TT  = 1024;
static constexpr int HID = 2048;
static constexpr int NH  = 16;
static constexpr int QL  = 768;
static constexpr int KVL = 512;
static constexpr int RD  = 64;     // rope dim
static constexpr int IH  = 32;     // idx heads
static constexpr int ID  = 128;    // idx dim
static constexpr int S1W = QL + KVL + RD + ID + IH;   // 1504
static constexpr int S3W = IH*ID + NH*(128+RD);       // 7168

#define SCALE_ATT 0.07216878364870323f   // 1/sqrt(192)
#define SC_IDXQ   0.08838834764831845f   // 1/sqrt(128)
#define SC_IDXW   0.17677669529663687f   // 1/sqrt(32)
#define NEGR      -1e30f
#define NEGL      -3.0e38f

typedef __bf16 bf16x8 __attribute__((ext_vector_type(8)));
typedef float  f32x4  __attribute__((ext_vector_type(4)));

// async global->LDS, 16 bytes per lane; dest = wave-uniform base + lane*16
#define GLD_LDS16(g, l) __builtin_amdgcn_global_load_lds( \
    (const __attribute__((address_space(1))) void*)(g),   \
    (__attribute__((address_space(3))) void*)(l), 16, 0, 0)

// bf16 <-> f32 helpers (RNE)
__device__ __forceinline__ unsigned short f2b(float x) {
  union { float f; unsigned u; } v; v.f = x;
  unsigned r = v.u + 0x7FFFu + ((v.u >> 16) & 1u);
  return (unsigned short)(r >> 16);
}
__device__ __forceinline__ float b2f(unsigned short u) {
  union { unsigned u; float f; } v; v.u = ((unsigned)u) << 16;
  return v.f;
}

// ===================== helpers =====================
__device__ __forceinline__ float blk_sum256(float v, float* s) {
  #pragma unroll
  for (int o = 32; o > 0; o >>= 1) v += __shfl_down(v, o, 64);
  __syncthreads();
  if ((threadIdx.x & 63) == 0) s[threadIdx.x >> 6] = v;
  __syncthreads();
  return s[0] + s[1] + s[2] + s[3];
}

// ===================== prelude: res = hs+resid; hb = bf16(rms(res)*w); + rope tables =====================
__global__ __launch_bounds__(256) void k_prelude(const float* __restrict__ hs,
                                                 const float* __restrict__ rsd,
                                                 const float* __restrict__ w,
                                                 const int* __restrict__ pos,
                                                 float* __restrict__ res,
                                                 unsigned short* __restrict__ hb,
                                                 float* __restrict__ cosb,
                                                 float* __restrict__ sinb) {
  int t = blockIdx.x;
  __shared__ float scr[4];
  if (threadIdx.x < 32) {        // fused rope cos/sin (fp64 internally)
    int k = threadIdx.x;
    double inv = pow(10000.0, -((double)(2*k))/64.0);
    double f = (double)pos[t] * inv;
    cosb[t*32 + k] = (float)cos(f);
    sinb[t*32 + k] = (float)sin(f);
  }
  float vals[8]; float ss = 0.f;
  #pragma unroll
  for (int r = 0; r < 8; r++) {
    int d = threadIdx.x + 256*r;
    float v = hs[(size_t)t*HID + d] + rsd[(size_t)t*HID + d];
    vals[r] = v; res[(size_t)t*HID + d] = v; ss = fmaf(v, v, ss);
  }
  ss = blk_sum256(ss, scr);
  float inv = 1.f/sqrtf(ss/(float)HID + 1e-6f);
  #pragma unroll
  for (int r = 0; r < 8; r++) {
    int d = threadIdx.x + 256*r;
    hb[(size_t)t*HID + d] = f2b(vals[r]*inv*w[d]);
  }
}

// res2 = attn1+attn2 + res -> d_out; h2 bf16; + fused routing logits/comb
__global__ __launch_bounds__(256) void k_res2g(const float* __restrict__ attn1,
                                               const float* __restrict__ attn2,
                                               const float* __restrict__ res,
                                               const float* __restrict__ w,
                                               const float* __restrict__ gw,
                                               const float* __restrict__ gb,
                                               float* __restrict__ res2_out,
                                               unsigned short* __restrict__ h2b,
                                               float* __restrict__ comb) {
  int t = blockIdx.x, tid = threadIdx.x;
  __shared__ float scr[4];
  __shared__ float h2l[HID];
  __shared__ float gl[8];
  float vals[8]; float ss = 0.f;
  #pragma unroll
  for (int r = 0; r < 8; r++) {
    int d = tid + 256*r;
    float v = attn1[(size_t)t*HID + d] + attn2[(size_t)t*HID + d] + res[(size_t)t*HID + d];
    vals[r] = v; res2_out[(size_t)t*HID + d] = v; ss = fmaf(v, v, ss);
  }
  ss = blk_sum256(ss, scr);
  float inv = 1.f/sqrtf(ss/(float)HID + 1e-6f);
  #pragma unroll
  for (int r = 0; r < 8; r++) {
    int d = tid + 256*r;
    float o = vals[r]*inv*w[d];
    h2l[d] = o;
    h2b[(size_t)t*HID + d] = f2b(o);
  }
  __syncthreads();
  int e = tid >> 5, lane = tid & 31;
  float p = 0.f;
  for (int d = lane; d < HID; d += 32) p = fmaf(h2l[d], gw[(size_t)e*HID + d], p);
  #pragma unroll
  for (int o = 16; o > 0; o >>= 1) p += __shfl_down(p, o, 32);
  if (lane == 0) gl[e] = p;
  __syncthreads();
  if (tid == 0) {
    float sg[8], sc[8];
    #pragma unroll
    for (int i = 0; i < 8; i++) { sg[i] = 1.f/(1.f+expf(-gl[i])); sc[i] = sg[i] + gb[i]; }
    float gs[4];
    #pragma unroll
    for (int g = 0; g < 4; g++) gs[g] = sc[2*g] + sc[2*g+1];
    int g0 = 0;
    for (int g = 1; g < 4; g++) if (gs[g] > gs[g0]) g0 = g;
    int g1 = -1;
    for (int g = 0; g < 4; g++) { if (g == g0) continue; if (g1 < 0 || gs[g] > gs[g1]) g1 = g; }
    float wsum = 1e-20f;
    #pragma unroll
    for (int i = 0; i < 8; i++) { int g = i >> 1; if (g == g0 || g == g1) wsum += sg[i]; }
    #pragma unroll
    for (int i = 0; i < 8; i++) { int g = i >> 1; comb[t*8+i] = (g == g0 || g == g1) ? sg[i]/wsum*2.5f : 0.f; }
  }
}

// ===================== f32 -> bf16 convert (with zero tail pad) =====================
__global__ void k_f2b(const float* __restrict__ s, unsigned short* __restrict__ d,
                      long long n, long long ntot) {
  long long stride = (long long)gridDim.x * 1024;
  for (long long i = ((long long)blockIdx.x*256 + threadIdx.x)*4; i < ntot; i += stride) {
    float x0, x1, x2, x3;
    if (i + 3 < n) { float4 v = *(const float4*)(s + i); x0=v.x; x1=v.y; x2=v.z; x3=v.w; }
    else {
      x0 = (i   < n) ? s[i]   : 0.f; x1 = (i+1 < n) ? s[i+1] : 0.f;
      x2 = (i+2 < n) ? s[i+2] : 0.f; x3 = (i+3 < n) ? s[i+3] : 0.f;
    }
    ushort4 o; o.x=f2b(x0); o.y=f2b(x1); o.z=f2b(x2); o.w=f2b(x3);
    *(ushort4*)(d + i) = o;
  }
}

// 4-segment fused convert (all n multiples of 4; trailing segments may be 0)
__global__ void k_f2b4(const float* __restrict__ s0, unsigned short* __restrict__ d0, long long n0,
                       const float* __restrict__ s1, unsigned short* __restrict__ d1, long long n1,
                       const float* __restrict__ s2, unsigned short* __restrict__ d2, long long n2,
                       const float* __restrict__ s3, unsigned short* __restrict__ d3, long long n3) {
  long long ntot = n0 + n1 + n2 + n3;
  long long stride = (long long)gridDim.x * 1024;
  for (long long i = ((long long)blockIdx.x*256 + threadIdx.x)*4; i < ntot; i += stride) {
    const float* s; unsigned short* d; long long j = i;
    if (j < n0) { s = s0; d = d0; }
    else { j -= n0;
      if (j < n1) { s = s1; d = d1; }
      else { j -= n1;
        if (j < n2) { s = s2; d = d2; }
        else { j -= n2; s = s3; d = d3; } } }
    float4 v = *(const float4*)(s + j);
    ushort4 o; o.x=f2b(v.x); o.y=f2b(v.y); o.z=f2b(v.z); o.w=f2b(v.w);
    *(ushort4*)(d + j) = o;
  }
}

// ===================== transpose + convert: src (R,C) f32 -> dst (C,R) bf16, batched z =====================
__global__ __launch_bounds__(256) void k_tconvb(const float* __restrict__ src,
                                                unsigned short* __restrict__ dst,
                                                int R, int C) {
  src += (size_t)blockIdx.z * R * C;
  dst += (size_t)blockIdx.z * R * C;
  __shared__ float tile[32][33];
  int c0 = blockIdx.x * 32, r0 = blockIdx.y * 32;
  int tx = threadIdx.x & 31, ty = threadIdx.x >> 5;
  #pragma unroll
  for (int i = 0; i < 4; i++) {
    int r = r0 + ty + i*8;
    tile[ty + i*8][tx] = src[(size_t)r*C + c0 + tx];
  }
  __syncthreads();
  #pragma unroll
  for (int i = 0; i < 4; i++) {
    int c = c0 + ty + i*8;
    dst[(size_t)c*R + r0 + tx] = f2b(tile[tx][ty + i*8]);
  }
}

// ===================== MFMA bf16 GEMM: C = alpha * A(M,K) @ B(N,K)^T =====================
// BM x 128 tile, BK in {64,128}, 4 waves (2x2), double-buffered LDS, prefetch-before-compute
// (round-10 schedule: STAGE(next) before compute(cur), one __syncthreads per K-step).
// Staging via global_load_lds width=16 (linear LDS dest + pre-swizzled per-lane source).
// OUT: 0 = f32 store, 1 = bf16 store, 2 = fused swiglu, 3 = indexer IL mode.
// ILV: B row permutation srow = (n>>1) + (n&1)*512 (gate/up interleave)
// MOE: 0 dense; 1 = gather-A by tokp, compact C rows; 2 = compact-A, compact C rows.
// cskip >= 0: skip block if col0 > row0+cskip. ktri: limit K to ceil128(row0+BM).
// nseg>1: segments (A += segA, B += segB). blockIdx.z advances A/B/C by sA/sB/sC.
template<int BM, int BK, int OUT, bool ILV, int MOE>
__global__ __launch_bounds__(256) void k_mgemm(
    const unsigned short* __restrict__ A, int lda, long long sA,
    const unsigned short* __restrict__ B, int ldb, long long sB,
    void* __restrict__ Cv, int ldc, long long sC,
    int N, int K, float alpha, int cskip, int ktri,
    int nseg, long long segA, long long segB,
    const float* __restrict__ comb,
    const int* __restrict__ cntp, const int* __restrict__ tokp) {
  constexpr int MR    = BM / 32;          // m-fragments per wave
  constexpr int SLOTS = BK / 8;           // 16B slots per row
  constexpr int SH    = (BK == 64) ? 3 : 4;
  constexpr int KC    = BK / 32;          // k-chunks per tile
  constexpr int ITA   = BM * SLOTS / 256; // A staging iterations
  constexpr int ITB   = 128 * SLOTS / 256;
  const int row0 = blockIdx.y * BM;
  const int col0 = blockIdx.x * 128;
  const int tid  = threadIdx.x;
  if (cskip >= 0 && col0 > row0 + cskip) {
    if (OUT == 3) {   // NEGR-fill the skipped tile (entirely in causal-masked region)
      float* C = (float*)Cv;
      for (int i = tid; i < BM*32; i += 256) {
        int rr = i >> 5, cc = (i & 31) * 4;
        float4 ng = make_float4(NEGR, NEGR, NEGR, NEGR);
        *(float4*)&C[(size_t)(row0 + rr)*ldc + col0 + cc] = ng;
      }
    }
    return;
  }
  const int zb = blockIdx.z;
  int cnt = 0; long long off = 0;
  if (MOE) {
    cnt = cntp[zb];
    for (int e = 0; e < zb; e++) off += cntp[e];
    if (row0 >= cnt) return;
  }
  __shared__ __align__(16) unsigned short As[2][BM*BK];
  __shared__ __align__(16) unsigned short Bs[2][128*BK];
  __shared__ float wlds[(OUT == 3) ? BM*32 : 1];
  const int wave = tid >> 6, lane = tid & 63;
  const int wm = wave >> 1, wn = wave & 1;
  A += (size_t)zb * (size_t)sA;
  B += (size_t)zb * (size_t)sB;
  if (MOE == 2) A += off * (long long)lda;

  if constexpr (OUT == 3) {   // stage idxw block: wlds[r*32+h] = idxw[(512+row0+r)*32+h]
    for (int i = tid; i < BM*32; i += 256)
      wlds[i] = comb[(size_t)(row0 + (i >> 5))*32 + (i & 31)];
  }

  int tki[ITA];
  if (MOE == 1) {
    #pragma unroll
    for (int it = 0; it < ITA; it++) {
      int r = (wave*64 + it*256 + lane) >> SH;
      tki[it] = tokp[zb*1024 + row0 + r];   // padded with 0 beyond cnt
    }
  }

  f32x4 acc[MR][4] = {};
  f32x4 acc2[(OUT == 3) ? MR : 1][4] = {};
  const int l15 = lane & 15, l4 = lane >> 4;
  const int sx = l15 & 7;
  int Kend = K;
  if (ktri) {
    int kub = (((row0 + BM - 1) >> 7) + 1) << 7;
    if (kub < Kend) Kend = kub;
  }
  const int nk = Kend / BK;
  const int nt = nseg * nk;

  auto STAGE = [&](int b, const unsigned short* Ab, const unsigned short* Bb, int k0) {
    #pragma unroll
    for (int it = 0; it < ITA; it++) {
      int base = wave*64 + it*256;        // wave-uniform
      int sidx = base + lane;
      int r = sidx >> SH, s = sidx & (SLOTS - 1);
      int s_src = s ^ (r & 7);            // pre-swizzled source slot
      const unsigned short* ga;
      if (MOE == 1) ga = Ab + (size_t)tki[it]*lda + k0 + s_src*8;
      else          ga = Ab + (size_t)(row0 + r)*lda + k0 + s_src*8;
      GLD_LDS16(ga, &As[b][base*8]);
    }
    #pragma unroll
    for (int it = 0; it < ITB; it++) {
      int base = wave*64 + it*256;
      int sidx = base + lane;
      int r = sidx >> SH, s = sidx & (SLOTS - 1);
      int s_src = s ^ (r & 7);
      int rt = col0 + r;
      int srow = ILV ? ((rt >> 1) + (rt & 1)*512) : rt;
      const unsigned short* gb = Bb + (size_t)srow*ldb + k0 + s_src*8;
      GLD_LDS16(gb, &Bs[b][base*8]);
    }
  };

  // prologue: stage tile 0
  STAGE(0, A, B, 0);
  int ks = BK, sg = 0;
  if (ks == Kend) { ks = 0; sg = 1; }
  __syncthreads();                         // drains vmcnt -> tile 0 resident (+ wlds visible)
  int cur = 0;

  for (int u = 0; u < nt; u++) {
    if (u + 1 < nt) {
      STAGE(cur ^ 1, A + (size_t)sg*segA, B + (size_t)sg*segB, ks);
      ks += BK;
      if (ks == Kend) { ks = 0; sg++; }
    }
    #pragma unroll
    for (int kc = 0; kc < KC; kc++) {
      const int sl = ((kc*4 + l4) ^ sx) << 3;
      bf16x8 fa[MR], fb[4];
      #pragma unroll
      for (int mf = 0; mf < MR; mf++)
        fa[mf] = *(const bf16x8*)&As[cur][(wm*(BM/2) + mf*16 + l15)*BK + sl];
      #pragma unroll
      for (int nf = 0; nf < 4; nf++)
        fb[nf] = *(const bf16x8*)&Bs[cur][(wn*64 + nf*16 + l15)*BK + sl];
      #pragma unroll
      for (int mf = 0; mf < MR; mf++)
        #pragma unroll
        for (int nf = 0; nf < 4; nf++)
          acc[mf][nf] = __builtin_amdgcn_mfma_f32_16x16x32_bf16(fa[mf], fb[nf], acc[mf][nf], 0, 0, 0);
    }
    if constexpr (OUT == 3) {   // end-of-segment fold: acc2 += relu(acc)*w[t,h]; acc = 0
      if ((u + 1) % nk == 0) {
        int h = u / nk;
        #pragma unroll
        for (int mf = 0; mf < MR; mf++) {
          #pragma unroll
          for (int r = 0; r < 4; r++) {
            int rl = wm*(BM/2) + mf*16 + l4*4 + r;
            float w = wlds[rl*32 + h];
            #pragma unroll
            for (int nf = 0; nf < 4; nf++) {
              acc2[mf][nf][r] += fmaxf(acc[mf][nf][r], 0.f) * w;
              acc[mf][nf][r] = 0.f;
            }
          }
        }
      }
    }
    __syncthreads();                       // drains vmcnt -> next tile resident
    cur ^= 1;
  }

  // C write: col = lane&15, row = (lane>>4)*4 + reg  [m89-verified]
  #pragma unroll
  for (int mf = 0; mf < MR; mf++) {
    #pragma unroll
    for (int nf = 0; nf < 4; nf++) {
      int n = col0 + wn*64 + nf*16 + l15;
      #pragma unroll
      for (int r = 0; r < 4; r++) {
        int m = row0 + wm*(BM/2) + mf*16 + l4*4 + r;
        if (OUT == 3) {
          float v = acc2[mf][nf][r];
          if (n > 512 + m) v = NEGR;       // causal mask (t = 512 + m)
          ((float*)Cv)[(size_t)m*ldc + n] = v;
          continue;
        }
        float v = acc[mf][nf][r] * alpha;
        if (OUT == 2) {
          float p = __shfl_xor(v, 1, 64);     // pair lane exchange (g,u)
          if ((l15 & 1) == 0) {
            bool ok = true;
            long long mrow = m;
            float w;
            if (MOE == 1) {
              ok = (m < cnt); mrow = off + m;
              int tok = tokp[zb*1024 + m];
              w = (zb < 8) ? comb[tok*8 + zb] : 1.f;
            } else {
              w = (zb < 8) ? comb[m*8 + zb] : 1.f;
            }
            if (ok) {
              float rres = v/(1.f + expf(-v)) * p * w;
              ((unsigned short*)Cv)[(size_t)zb*sC + (size_t)mrow*ldc + (n >> 1)] = f2b(rres);
            }
          }
        } else if (n < N) {
          bool ok = true;
          long long mrow = m;
          if (MOE == 2) { ok = (m < cnt); mrow = off + m; }
          if (ok) {
            size_t idx = (size_t)mrow*ldc + n;
            if (OUT == 1) ((unsigned short*)Cv)[(size_t)zb*sC + idx] = f2b(v);
            else          ((float*)Cv)[(size_t)zb*sC + idx] = v;
          }
        }
      }
    }
  }
}

// ===================== post-s1 (sums 2 split-K partials; writes KVB/IDXKB bf16 directly) =====================
__global__ __launch_bounds__(256) void k_post1(const float* __restrict__ s1a,
    const float* __restrict__ s1b,
    const float* __restrict__ wq, const float* __restrict__ wkv,
    const float* __restrict__ lnw, const float* __restrict__ lnb,
    const float* __restrict__ cosb, const float* __restrict__ sinb,
    unsigned short* __restrict__ qcb, float* __restrict__ kvc,
    unsigned short* __restrict__ kvb, unsigned short* __restrict__ idxkb,
    float* __restrict__ idxw) {
  int t = blockIdx.x, tid = threadIdx.x;
  __shared__ float rowb[S1W];
  __shared__ float scr[4];
  __shared__ float yb[128];
  for (int d = tid; d < S1W; d += 256)
    rowb[d] = s1a[(size_t)t*S1W + d] + s1b[(size_t)t*S1W + d];
  __syncthreads();
  float ss = 0.f;
  for (int d = tid; d < QL; d += 256) { float v = rowb[d]; ss = fmaf(v,v,ss); }
  ss = blk_sum256(ss, scr);
  float inv = 1.f/sqrtf(ss/(float)QL + 1e-6f);
  for (int d = tid; d < QL; d += 256) qcb[(size_t)t*QL + d] = f2b(rowb[d]*inv*wq[d]);
  ss = 0.f;
  for (int d = tid; d < KVL; d += 256) { float v = rowb[QL+d]; ss = fmaf(v,v,ss); }
  ss = blk_sum256(ss, scr);
  inv = 1.f/sqrtf(ss/(float)KVL + 1e-6f);
  for (int d = tid; d < KVL; d += 256) {
    float v = rowb[QL+d]*inv*wkv[d];
    kvc[(size_t)t*KVL + d] = v;
    kvb[(size_t)t*576 + d] = f2b(v);
  }
  float sm = (tid < 128) ? rowb[1344 + tid] : 0.f;
  float tot = blk_sum256(sm, scr);
  float mean = tot / 128.f;
  float vs = 0.f;
  if (tid < 128) { float v = rowb[1344+tid] - mean; vs = v*v; }
  vs = blk_sum256(vs, scr);
  float ivn = 1.f/sqrtf(vs/128.f + 1e-6f);
  if (tid < 128) yb[tid] = (rowb[1344+tid]-mean)*ivn*lnw[tid] + lnb[tid];
  __syncthreads();
  if (tid < 32) {
    float c = cosb[t*32 + tid], s = sinb[t*32 + tid];
    idxkb[(size_t)t*ID + tid]      = f2b(yb[tid]*c - yb[32+tid]*s);
    idxkb[(size_t)t*ID + 32 + tid] = f2b(yb[32+tid]*c + yb[tid]*s);
    float x1 = rowb[1280+tid], x2 = rowb[1312+tid];
    kvb[(size_t)t*576 + 512 + tid] = f2b(x1*c - x2*s);
    kvb[(size_t)t*576 + 544 + tid] = f2b(x2*c + x1*s);
    idxw[(size_t)t*IH + tid] = rowb[1472+tid] * SC_IDXW;
  } else if (tid >= 64 && tid < 128) {
    idxkb[(size_t)t*ID + tid] = f2b(yb[tid]);
  }
}

// ===================== post-s3: rope/scale in LDS; writes S3B bf16 + QMQAB pe cols =====================
__global__ __launch_bounds__(256) void k_post3b(const float* __restrict__ s3,
                                                const float* __restrict__ cosb,
                                                const float* __restrict__ sinb,
                                                unsigned short* __restrict__ s3b,
                                                unsigned short* __restrict__ qm) {
  int t = blockIdx.x, tid = threadIdx.x;
  const float* row = s3 + (size_t)t*S3W;
  __shared__ float buf[S3W];
  __shared__ float cs[32], sn[32];
  if (tid < 32) { cs[tid] = cosb[t*32+tid]; sn[tid] = sinb[t*32+tid]; }
  for (int d = tid; d < S3W; d += 256) buf[d] = row[d];
  __syncthreads();
  for (int p = tid; p < 1024; p += 256) {
    int h = p >> 5, d = p & 31;
    float c = cs[d], s = sn[d];
    float x1 = buf[h*ID + d], x2 = buf[h*ID + 32 + d];
    buf[h*ID + d]      = (x1*c - x2*s) * SC_IDXQ;
    buf[h*ID + 32 + d] = (x2*c + x1*s) * SC_IDXQ;
  }
  for (int p = tid; p < 2048; p += 256) {
    int h = p >> 6, d = 64 + (p & 63);
    buf[h*ID + d] *= SC_IDXQ;
  }
  for (int p = tid; p < 512; p += 256) {
    int h = p >> 5, d = p & 31;
    float c = cs[d], s = sn[d];
    int base = IH*ID + h*192 + 128;
    float x1 = buf[base + d], x2 = buf[base + 32 + d];
    float r1 = x1*c - x2*s, r2 = x2*c + x1*s;
    buf[base + d]      = r1;
    buf[base + 32 + d] = r2;
    qm[(size_t)t*9216 + h*576 + 512 + d] = f2b(r1 * SCALE_ATT);
    qm[(size_t)t*9216 + h*576 + 544 + d] = f2b(r2 * SCALE_ATT);
  }
  __syncthreads();
  unsigned short* orow = s3b + (size_t)t*S3W;
  for (int g = tid*4; g < S3W; g += 1024) {
    ushort4 o;
    o.x = f2b(buf[g]); o.y = f2b(buf[g+1]); o.z = f2b(buf[g+2]); o.w = f2b(buf[g+3]);
    *(ushort4*)(orow + g) = o;
  }
}

// ===================== exact per-row top-512 (bitonic, tie -> lower index) =====================
__global__ __launch_bounds__(512) void k_topk(const float* __restrict__ isc,
                                              unsigned char* __restrict__ mask) {
  int t = 512 + blockIdx.x;
  const float* row = isc + (size_t)blockIdx.x * TT;
  __shared__ unsigned long long keys[1024];
  int tid = threadIdx.x;
  for (int i = tid; i < 1024; i += 512) {
    float v = row[i];
    unsigned int b = __float_as_uint(v);
    unsigned int u = (b & 0x80000000u) ? ~b : (b | 0x80000000u);
    keys[i] = ((unsigned long long)u << 32) | (unsigned int)(1023 - i);
  }
  __syncthreads();
  for (int k = 2; k <= 1024; k <<= 1) {
    for (int j = k >> 1; j > 0; j >>= 1) {
      int i = ((tid & ~(j - 1)) << 1) | (tid & (j - 1));
      int l = i | j;
      unsigned long long a = keys[i], b = keys[l];
      bool up = ((i & k) == 0);
      if ((a < b) == up) { keys[i] = b; keys[l] = a; }
      __syncthreads();
    }
  }
  unsigned char* mrow = mask + (size_t)t * TT;
  for (int p = tid; p < 1024; p += 512) {
    int s = 1023 - (int)(keys[p] & 0xFFFFFFFFu);
    mrow[s] = (p < 512) ? (unsigned char)1 : (unsigned char)0;
  }
}

// ===================== masked softmax over P rows (in place, bf16; width-limited) =====================
__global__ __launch_bounds__(256) void k_psoft(unsigned short* __restrict__ pb,
                                               const unsigned char* __restrict__ mask) {
  int b = blockIdx.x;
  int t = b & 1023, h = b >> 10;
  unsigned short* row = pb + ((size_t)h << 20) + ((size_t)t << 10);
  int tid = threadIdx.x;
  __shared__ float scr[4];
  int s0 = tid * 4;
  int rub = ((t >> 7) + 1) << 7;       // PV (ktri) reads cols < rub only
  bool act = (s0 < rub);
  float v0 = 0.f, v1 = 0.f, v2 = 0.f, v3 = 0.f;
  bool m0 = false, m1 = false, m2 = false, m3 = false;
  if (act) {
    ushort4 raw = *(const ushort4*)(row + s0);
    v0 = b2f(raw.x); v1 = b2f(raw.y); v2 = b2f(raw.z); v3 = b2f(raw.w);
    if (t < 512) {
      m0 = (s0 <= t); m1 = (s0+1 <= t); m2 = (s0+2 <= t); m3 = (s0+3 <= t);
    } else {
      uchar4 mk = *(const uchar4*)(mask + (size_t)t*TT + s0);
      m0 = (s0 <= t) && mk.x; m1 = (s0+1 <= t) && mk.y;
      m2 = (s0+2 <= t) && mk.z; m3 = (s0+3 <= t) && mk.w;
    }
  }
  float mx = NEGL;
  if (m0) mx = v0;
  if (m1) mx = fmaxf(mx, v1);
  if (m2) mx = fmaxf(mx, v2);
  if (m3) mx = fmaxf(mx, v3);
  #pragma unroll
  for (int o = 32; o > 0; o >>= 1) mx = fmaxf(mx, __shfl_down(mx, o, 64));
  __syncthreads();
  if ((tid & 63) == 0) scr[tid >> 6] = mx;
  __syncthreads();
  mx = fmaxf(fmaxf(scr[0], scr[1]), fmaxf(scr[2], scr[3]));
  float p0 = m0 ? expf(v0 - mx) : 0.f;
  float p1 = m1 ? expf(v1 - mx) : 0.f;
  float p2 = m2 ? expf(v2 - mx) : 0.f;
  float p3 = m3 ? expf(v3 - mx) : 0.f;
  float sum = blk_sum256((p0+p1)+(p2+p3), scr);
  float inv = 1.f / sum;
  if (act) {
    ushort4 o;
    o.x = f2b(p0*inv); o.y = f2b(p1*inv); o.z = f2b(p2*inv); o.w = f2b(p3*inv);
    *(ushort4*)(row + s0) = o;
  }
}

// ===================== routing compaction: per-expert stable token lists =====================
__global__ __launch_bounds__(1024) void k_route(const float* __restrict__ comb,
                                                int* __restrict__ tokidx,
                                                int* __restrict__ rank,
                                                int* __restrict__ cntp) {
  int e = blockIdx.x;   // 0..8 (8 = shared identity)
  int t = threadIdx.x;  // 0..1023
  if (e == 8) {
    tokidx[8*1024 + t] = t;
    if (t == 0) cntp[8] = 1024;
    return;
  }
  int lane = t & 63, w = t >> 6;
  bool sel = comb[t*8 + e] != 0.0f;
  unsigned long long bal = __ballot(sel);
  int pw = __popcll(bal & ((1ull << lane) - 1ull));
  int wt = __popcll(bal);
  __shared__ int wsum[16];
  if (lane == 0) wsum[w] = wt;
  __syncthreads();
  int woff = 0, total = 0;
  #pragma unroll
  for (int i = 0; i < 16; i++) { int v = wsum[i]; if (i < w) woff += v; total += v; }
  int pos = woff + pw;
  rank[t*8 + e] = sel ? pos : -1;
  if (sel) tokidx[e*1024 + pos] = t;
  __syncthreads();
  if (t >= total) tokidx[e*1024 + t] = 0;  // pad
  if (t == 0) cntp[e] = total;
}

// ===================== gather-sum: out[t] = shared + sum_e selected expert rows (bf16 DPC) =====================
__global__ __launch_bounds__(256) void k_rsum(const unsigned short* __restrict__ dpc,
                                              const int* __restrict__ rank,
                                              const int* __restrict__ cntp,
                                              float* __restrict__ out) {
  int t = blockIdx.x;
  int d = threadIdx.x * 8;
  int offs[8]; int acc_off = 0;
  #pragma unroll
  for (int e = 0; e < 8; e++) { offs[e] = acc_off; acc_off += cntp[e]; }
  const unsigned short* ps = dpc + (size_t)(acc_off + t)*2048 + d;   // shared row
  ushort4 u0 = *(const ushort4*)ps;
  ushort4 u1 = *(const ushort4*)(ps + 4);
  float a[8];
  a[0]=b2f(u0.x); a[1]=b2f(u0.y); a[2]=b2f(u0.z); a[3]=b2f(u0.w);
  a[4]=b2f(u1.x); a[5]=b2f(u1.y); a[6]=b2f(u1.z); a[7]=b2f(u1.w);
  #pragma unroll
  for (int e = 0; e < 8; e++) {
    int r = rank[t*8 + e];
    if (r >= 0) {
      const unsigned short* p = dpc + (size_t)(offs[e] + r)*2048 + d;
      ushort4 b0 = *(const ushort4*)p;
      ushort4 b1 = *(const ushort4*)(p + 4);
      a[0]+=b2f(b0.x); a[1]+=b2f(b0.y); a[2]+=b2f(b0.z); a[3]+=b2f(b0.w);
      a[4]+=b2f(b1.x); a[5]+=b2f(b1.y); a[6]+=b2f(b1.z); a[7]+=b2f(b1.w);
    }
  }
  float* po = out + (size_t)t*2048 + d;
  *(float4*)po       = make_float4(a[0], a[1], a[2], a[3]);
  *(float4*)(po + 4) = make_float4(a[4], a[5], a[6], a[7]);
}

// ===================== launch =====================
extern "C" void kernel_launch(void* const* d_in, const int* in_sizes, int n_in,
                              void* d_out, int out_size, void* d_ws, size_t ws_size,
                              hipStream_t stream) {
  const int*   positions = (const int*)d_in[0];
  const float* hs     = (const float*)d_in[1];
  const float* rsd    = (const float*)d_in[2];
  const float* w_in   = (const float*)d_in[3];
  const float* w_post = (const float*)d_in[4];
  const float* w_s1   = (const float*)d_in[5];
  const float* w_qln  = (const float*)d_in[6];
  const float* w_kvln = (const float*)d_in[7];
  const float* iklnw  = (const float*)d_in[8];
  const float* iklnb  = (const float*)d_in[9];
  const float* w_s3   = (const float*)d_in[10];
  const float* wukt   = (const float*)d_in[11];
  const float* wuv    = (const float*)d_in[12];
  const float* w_o    = (const float*)d_in[13];
  const float* gate_w = (const float*)d_in[14];
  const float* gate_b = (const float*)d_in[15];
  const float* sh_gu  = (const float*)d_in[16];
  const float* sh_dn  = (const float*)d_in[17];
  const float* ex_gu  = (const float*)d_in[18];
  const float* ex_dn  = (const float*)d_in[19];

  float* ws = (float*)d_ws;
  typedef unsigned short ush;
  // -------- workspace layout (float units), phase-disjoint aliasing; peak 34,152,448 f = 136.6 MB --------
  // persistent
  float* RES   = ws + 0;          // 2,097,152
  float* COSB  = ws + 2097152;    // 32,768
  float* SINB  = ws + 2129920;    // 32,768
  float* KVC   = ws + 2162688;    // 524,288
  float* IDXW  = ws + 2883584;    // 32,768
  float* COMB  = ws + 2916352;    // 8,192
  // phase A
  ush*   HB    = (ush*)(ws + 2924544);   // 2,097,152 ush -> ends f 3,973,120
  ush*   WS1B  = (ush*)(ws + 3973120);   // 3,145,728 ush (1536x2048 padded) -> ends f 5,545,984
  float* S1P0  = ws + 5545984;           // 1,540,096 -> ends 7,086,080
  ush*   QCB   = (ush*)(ws + 7086080);   // 786,432 ush -> ends f 7,479,296
  ush*   WS3B  = (ush*)(ws + 7479296);   // 5,505,024 ush -> ends f 10,231,808
  float* S3    = ws + 10231808;          // 7,340,032 f32 -> ends 17,571,840
  float* S1P1  = ws + 10231808;          // 1,540,096 (split-K partial 1; dead before S3 write)
  ush*   S3B   = (ush*)(ws + 17571840);  // 7,340,032 ush -> ends f 21,241,856
  ush*   WUKTB = (ush*)(ws + 21241856);  // 1,048,576 ush -> ends f 21,766,144
  ush*   QMQAB = (ush*)(ws + 21766144);  // 9,437,184 ush : [t][h][576] -> ends f 26,484,736
  float* ISC   = ws + 26484736;          // 524,288 -> ends 27,009,024
  unsigned char* MASK = (unsigned char*)(ws + 27009024); // 1,048,576 B -> ends f 27,271,168
  ush*   WUVB  = (ush*)(ws + 27271168);  // 1,048,576 ush -> ends f 27,795,456
  ush*   KVB   = (ush*)(ws + 27795456);  // 589,824 ush -> ends f 28,090,368
  ush*   VTB   = (ush*)(ws + 28090368);  // 524,288 ush : V^T (512,1024) -> ends f 28,352,512
  ush*   O2B   = (ush*)(ws + 28352512);  // 2,097,152 ush -> ends f 29,401,088
  ush*   IDXKB = (ush*)(ws + 31989760);  // 131,072 ush -> ends f 32,055,296
  ush*   WOB   = (ush*)(ws + 32055296);  // 4,194,304 ush (w_o bf16; own region) -> ends f 34,152,448
  ush*   PB    = (ush*)(ws + 10231808);  // 16,777,216 ush : [h][t][1024] (overlays dead S3/S3B head)
  ush*   OHB   = (ush*)(ws + 18620416);  // 8,388,608 ush : [h][t][512] (overlays dead S3B tail/WUKTB/QMQAB head)
  float* ATTNP = ws + 10231808;          // 2 x 2,097,152 (split-K partials; overlays dead PB)
  // phase B (all written after k_res2g)
  ush*   H2B    = (ush*)(ws + 5021696);  // 2,097,152 ush -> ends f 6,070,272
  ush*   EXGUB  = (ush*)(ws + 6070272);  // 16,777,216 ush -> ends f 14,458,880
  ush*   SHGUB  = (ush*)(ws + 14458880); // 2,097,152 ush (contiguous after EXGUB => z=8)
  ush*   EXDNB  = (ush*)(ws + 15507456); // 8,388,608 ush -> ends f 19,701,760
  ush*   SHDNB  = (ush*)(ws + 19701760); // 1,048,576 ush (contiguous => expert 8)
  ush*   ACTC   = (ush*)(ws + 20226048); // 5120x512 ush compacted acts -> ends f 21,536,768
  ush*   DPC    = (ush*)(ws + 21536768); // 5120x2048 ush compacted down outputs -> ends f 26,779,648
  int*   TOKIDX = (int*)(ws + 32022528); // 9x1024 int (phase-B; overlays dead IDXKB tail)
  int*   RANK   = (int*)(ws + 32031744); // 1024x8 int
  int*   CNT    = (int*)(ws + 32039936); // 16 int

  float* OUT0 = (float*)d_out;
  float* OUT_RES2 = OUT0 + (size_t)TT*HID;

  // 1. prelude (+ fused rope tables)
  k_prelude<<<TT, 256, 0, stream>>>(hs, rsd, w_in, positions, RES, HB, COSB, SINB);
  // 2. early weight conversions: w_s1 (padded), then w_s3|w_o fused, transposed wukt/wuv
  k_f2b<<<1024, 256, 0, stream>>>(w_s1, WS1B, 3080192LL, 3145728LL);
  k_f2b4<<<2048, 256, 0, stream>>>(w_s3, WS3B, 5505024LL,
                                   w_o,  WOB,  4194304LL,
                                   w_s3, WS3B, 0LL,
                                   w_s3, WS3B, 0LL);
  k_tconvb<<<dim3(16,4,16), 256, 0, stream>>>(wukt, WUKTB, 128, 512);
  k_tconvb<<<dim3(4,16,16), 256, 0, stream>>>(wuv, WUVB, 512, 128);
  // 3. s1 = h @ w_s1^T, split-K z=2 (K halves of 1024) -> partials   [BK=128]
  k_mgemm<128,128,0,false,0><<<dim3(12,8,2), 256, 0, stream>>>(
      HB, 2048, 1024, WS1B, 2048, 1024, S1P0, S1W, 4685824,
      1504, 1024, 1.f, -1, 0, 1, 0, 0, nullptr, nullptr, nullptr);
  // 4. post-s1 (sums partials); writes QCB, KVC f32, KVB bf16 concat, IDXKB bf16, IDXW
  k_post1<<<TT, 256, 0, stream>>>(S1P0, S1P1, w_qln, w_kvln, iklnw, iklnb, COSB, SINB,
                                  QCB, KVC, KVB, IDXKB, IDXW);
  // 5. s3 = q_c @ w_s3^T   [BK=128, K=768]
  k_mgemm<128,128,0,false,0><<<dim3(56,8,1), 256, 0, stream>>>(
      QCB, 768, 0, WS3B, 768, 0, S3, S3W, 0,
      S3W, 768, 1.f, -1, 0, 1, 0, 0, nullptr, nullptr, nullptr);
  // 6. post-s3: rope/scale + bf16 write + QMQAB pe cols fused
  k_post3b<<<TT, 256, 0, stream>>>(S3, COSB, SINB, (ush*)S3B, QMQAB);
  // 7. ql_nope -> QMQAB[:, :, 0:512] (SCALE_ATT folded)   [BK=64, K=128]
  k_mgemm<128,64,1,false,0><<<dim3(4,8,16), 256, 0, stream>>>(
      S3B + 4096, S3W, 192, WUKTB, 128, 65536, QMQAB, 9216, 576,
      512, 128, SCALE_ATT, -1, 0, 1, 0, 0, nullptr, nullptr, nullptr);
  // 8. indexer scores: fused 32 head-segments, relu-weighted fold -> ISC (causal NEGR)
  k_mgemm<64,64,3,false,0><<<dim3(8,8,1), 256, 0, stream>>>(
      S3B + (size_t)512*S3W, S3W, 0, IDXKB, 128, 0,
      ISC, 1024, 0, 1024, 128, 1.f, 575, 0, 32, 128, 0,
      IDXW + (size_t)512*IH, nullptr, nullptr);
  // 9. exact top-512
  k_topk<<<512, 512, 0, stream>>>(ISC, MASK);
  // 10. V^T bf16
  k_tconvb<<<dim3(16,32,1), 256, 0, stream>>>(KVC, VTB, 1024, 512);
  // 11. logits P = Qmqa @ KV^T (per head), causal block-skip -> bf16   [BK=64, K=576]
  k_mgemm<128,64,1,false,0><<<dim3(8,8,16), 256, 0, stream>>>(
      QMQAB, 9216, 576, KVB, 576, 0, PB, 1024, 1048576,
      1024, 576, 1.f, 127, 0, 1, 0, 0, nullptr, nullptr, nullptr);
  // 12. masked softmax in place (zeros masked entries up to the 128-block bound)
  k_psoft<<<16384, 256, 0, stream>>>(PB, MASK);
  // 13. O = P @ V (per head), K truncated to causal bound (ktri) -> OHB bf16   [BK=128]
  k_mgemm<128,128,1,false,0><<<dim3(4,8,16), 256, 0, stream>>>(
      PB, 1024, 1048576, VTB, 1024, 0, OHB, 512, 524288,
      512, 1024, 1.f, -1, 1, 1, 0, 0, nullptr, nullptr, nullptr);
  // 14. o2 = O @ W_UV (per head) -> O2B [t][h*128]   [BK=128, K=512]
  k_mgemm<128,128,1,false,0><<<dim3(1,8,16), 256, 0, stream>>>(
      OHB, 512, 524288, WUVB, 512, 65536, O2B, 2048, 128,
      128, 512, 1.f, -1, 0, 1, 0, 0, nullptr, nullptr, nullptr);
  // 15. attn_out = o2 @ w_o^T, split-K z=2 -> partials   [BK=128]
  k_mgemm<128,128,0,false,0><<<dim3(16,8,2), 256, 0, stream>>>(
      O2B, 2048, 1024, WOB, 2048, 1024, ATTNP, 2048, 2097152,
      2048, 1024, 1.f, -1, 0, 1, 0, 0, nullptr, nullptr, nullptr);
  // 16. res2 (sums partials) + h2 bf16 + fused routing -> COMB
  k_res2g<<<TT, 256, 0, stream>>>(ATTNP, ATTNP + 2097152, RES, w_post, gate_w, gate_b,
                                  OUT_RES2, H2B, COMB);
  // 17. deterministic compaction
  k_route<<<9, 1024, 0, stream>>>(COMB, TOKIDX, RANK, CNT);
  // 18. fused late weight conversions (ex_gu | sh_gu | ex_dn | sh_dn)
  k_f2b4<<<2048, 256, 0, stream>>>(ex_gu, EXGUB, 16777216LL,
                                   sh_gu, SHGUB, 2097152LL,
                                   ex_dn, EXDNB, 8388608LL,
                                   sh_dn, SHDNB, 1048576LL);
  // 19. sparse gate-up (9 experts incl shared), A gathered by TOKIDX, swiglu+comb fused  [BK=128]
  k_mgemm<128,128,2,true,1><<<dim3(8,8,9), 256, 0, stream>>>(
      H2B, 2048, 0, EXGUB, 2048, 2097152, ACTC, 512, 0,
      1024, 2048, 1.f, -1, 0, 1, 0, 0, COMB, CNT, TOKIDX);
  // 20. sparse down-proj per expert: DPC[off_e + i][2048] bf16   [BK=128, K=512]
  k_mgemm<128,128,1,false,2><<<dim3(16,8,9), 256, 0, stream>>>(
      ACTC, 512, 0, EXDNB, 512, 1048576, DPC, 2048, 0,
      2048, 512, 1.f, -1, 0, 1, 0, 0, nullptr, CNT, nullptr);
  // 21. out[t] = shared + sum of t's selected expert rows (fixed ascending-e order)
  k_rsum<<<TT, 256, 0, stream>>>(DPC, RANK, CNT, OUT0);
}

// Round 15
// 419.370 us; speedup vs baseline: 1.1463x; 1.1463x over previous
//
#include <hip/hip_runtime.h>
#include <math.h>

// ===================== constants =====================
static constexpr int TT  = 1024;
static constexpr int HID = 2048;
static constexpr int NH  = 16;
static constexpr int QL  = 768;
static constexpr int KVL = 512;
static constexpr int RD  = 64;     // rope dim
static constexpr int IH  = 32;     // idx heads
static constexpr int ID  = 128;    // idx dim
static constexpr int S1W = QL + KVL + RD + ID + IH;   // 1504
static constexpr int S3W = IH*ID + NH*(128+RD);       // 7168

#define SCALE_ATT 0.07216878364870323f   // 1/sqrt(192)
#define SC_IDXQ   0.08838834764831845f   // 1/sqrt(128)
#define SC_IDXW   0.17677669529663687f   // 1/sqrt(32)
#define NEGR      -1e30f
#define NEGL      -3.0e38f

typedef __bf16 bf16x8 __attribute__((ext_vector_type(8)));
typedef float  f32x4  __attribute__((ext_vector_type(4)));

// async global->LDS, 16 bytes per lane; dest = wave-uniform base + lane*16
#define GLD_LDS16(g, l) __builtin_amdgcn_global_load_lds( \
    (const __attribute__((address_space(1))) void*)(g),   \
    (__attribute__((address_space(3))) void*)(l), 16, 0, 0)

// bf16 <-> f32 helpers (RNE)
__device__ __forceinline__ unsigned short f2b(float x) {
  union { float f; unsigned u; } v; v.f = x;
  unsigned r = v.u + 0x7FFFu + ((v.u >> 16) & 1u);
  return (unsigned short)(r >> 16);
}
__device__ __forceinline__ float b2f(unsigned short u) {
  union { unsigned u; float f; } v; v.u = ((unsigned)u) << 16;
  return v.f;
}

// ===================== helpers =====================
__device__ __forceinline__ float blk_sum256(float v, float* s) {
  #pragma unroll
  for (int o = 32; o > 0; o >>= 1) v += __shfl_down(v, o, 64);
  __syncthreads();
  if ((threadIdx.x & 63) == 0) s[threadIdx.x >> 6] = v;
  __syncthreads();
  return s[0] + s[1] + s[2] + s[3];
}

// ===================== prelude: res = hs+resid; hb = bf16(rms(res)*w); + rope tables =====================
__global__ __launch_bounds__(256) void k_prelude(const float* __restrict__ hs,
                                                 const float* __restrict__ rsd,
                                                 const float* __restrict__ w,
                                                 const int* __restrict__ pos,
                                                 float* __restrict__ res,
                                                 unsigned short* __restrict__ hb,
                                                 float* __restrict__ cosb,
                                                 float* __restrict__ sinb) {
  int t = blockIdx.x;
  __shared__ float scr[4];
  if (threadIdx.x < 32) {        // fused rope cos/sin (fp64 internally)
    int k = threadIdx.x;
    double inv = pow(10000.0, -((double)(2*k))/64.0);
    double f = (double)pos[t] * inv;
    cosb[t*32 + k] = (float)cos(f);
    sinb[t*32 + k] = (float)sin(f);
  }
  float vals[8]; float ss = 0.f;
  #pragma unroll
  for (int r = 0; r < 8; r++) {
    int d = threadIdx.x + 256*r;
    float v = hs[(size_t)t*HID + d] + rsd[(size_t)t*HID + d];
    vals[r] = v; res[(size_t)t*HID + d] = v; ss = fmaf(v, v, ss);
  }
  ss = blk_sum256(ss, scr);
  float inv = 1.f/sqrtf(ss/(float)HID + 1e-6f);
  #pragma unroll
  for (int r = 0; r < 8; r++) {
    int d = threadIdx.x + 256*r;
    hb[(size_t)t*HID + d] = f2b(vals[r]*inv*w[d]);
  }
}

// res2 = attn1+attn2 + res -> d_out; h2 bf16; + fused routing logits/comb
__global__ __launch_bounds__(256) void k_res2g(const float* __restrict__ attn1,
                                               const float* __restrict__ attn2,
                                               const float* __restrict__ res,
                                               const float* __restrict__ w,
                                               const float* __restrict__ gw,
                                               const float* __restrict__ gb,
                                               float* __restrict__ res2_out,
                                               unsigned short* __restrict__ h2b,
                                               float* __restrict__ comb) {
  int t = blockIdx.x, tid = threadIdx.x;
  __shared__ float scr[4];
  __shared__ float h2l[HID];
  __shared__ float gl[8];
  float vals[8]; float ss = 0.f;
  #pragma unroll
  for (int r = 0; r < 8; r++) {
    int d = tid + 256*r;
    float v = attn1[(size_t)t*HID + d] + attn2[(size_t)t*HID + d] + res[(size_t)t*HID + d];
    vals[r] = v; res2_out[(size_t)t*HID + d] = v; ss = fmaf(v, v, ss);
  }
  ss = blk_sum256(ss, scr);
  float inv = 1.f/sqrtf(ss/(float)HID + 1e-6f);
  #pragma unroll
  for (int r = 0; r < 8; r++) {
    int d = tid + 256*r;
    float o = vals[r]*inv*w[d];
    h2l[d] = o;
    h2b[(size_t)t*HID + d] = f2b(o);
  }
  __syncthreads();
  int e = tid >> 5, lane = tid & 31;
  float p = 0.f;
  for (int d = lane; d < HID; d += 32) p = fmaf(h2l[d], gw[(size_t)e*HID + d], p);
  #pragma unroll
  for (int o = 16; o > 0; o >>= 1) p += __shfl_down(p, o, 32);
  if (lane == 0) gl[e] = p;
  __syncthreads();
  if (tid == 0) {
    float sg[8], sc[8];
    #pragma unroll
    for (int i = 0; i < 8; i++) { sg[i] = 1.f/(1.f+expf(-gl[i])); sc[i] = sg[i] + gb[i]; }
    float gs[4];
    #pragma unroll
    for (int g = 0; g < 4; g++) gs[g] = sc[2*g] + sc[2*g+1];
    int g0 = 0;
    for (int g = 1; g < 4; g++) if (gs[g] > gs[g0]) g0 = g;
    int g1 = -1;
    for (int g = 0; g < 4; g++) { if (g == g0) continue; if (g1 < 0 || gs[g] > gs[g1]) g1 = g; }
    float wsum = 1e-20f;
    #pragma unroll
    for (int i = 0; i < 8; i++) { int g = i >> 1; if (g == g0 || g == g1) wsum += sg[i]; }
    #pragma unroll
    for (int i = 0; i < 8; i++) { int g = i >> 1; comb[t*8+i] = (g == g0 || g == g1) ? sg[i]/wsum*2.5f : 0.f; }
  }
}

// ===================== f32 -> bf16 convert (with zero tail pad) =====================
__global__ void k_f2b(const float* __restrict__ s, unsigned short* __restrict__ d,
                      long long n, long long ntot) {
  long long stride = (long long)gridDim.x * 1024;
  for (long long i = ((long long)blockIdx.x*256 + threadIdx.x)*4; i < ntot; i += stride) {
    float x0, x1, x2, x3;
    if (i + 3 < n) { float4 v = *(const float4*)(s + i); x0=v.x; x1=v.y; x2=v.z; x3=v.w; }
    else {
      x0 = (i   < n) ? s[i]   : 0.f; x1 = (i+1 < n) ? s[i+1] : 0.f;
      x2 = (i+2 < n) ? s[i+2] : 0.f; x3 = (i+3 < n) ? s[i+3] : 0.f;
    }
    ushort4 o; o.x=f2b(x0); o.y=f2b(x1); o.z=f2b(x2); o.w=f2b(x3);
    *(ushort4*)(d + i) = o;
  }
}

// 4-segment fused convert (all n multiples of 4; trailing segments may be 0)
__global__ void k_f2b4(const float* __restrict__ s0, unsigned short* __restrict__ d0, long long n0,
                       const float* __restrict__ s1, unsigned short* __restrict__ d1, long long n1,
                       const float* __restrict__ s2, unsigned short* __restrict__ d2, long long n2,
                       const float* __restrict__ s3, unsigned short* __restrict__ d3, long long n3) {
  long long ntot = n0 + n1 + n2 + n3;
  long long stride = (long long)gridDim.x * 1024;
  for (long long i = ((long long)blockIdx.x*256 + threadIdx.x)*4; i < ntot; i += stride) {
    const float* s; unsigned short* d; long long j = i;
    if (j < n0) { s = s0; d = d0; }
    else { j -= n0;
      if (j < n1) { s = s1; d = d1; }
      else { j -= n1;
        if (j < n2) { s = s2; d = d2; }
        else { j -= n2; s = s3; d = d3; } } }
    float4 v = *(const float4*)(s + j);
    ushort4 o; o.x=f2b(v.x); o.y=f2b(v.y); o.z=f2b(v.z); o.w=f2b(v.w);
    *(ushort4*)(d + j) = o;
  }
}

// ===================== transpose + convert: src (R,C) f32 -> dst (C,R) bf16, batched z =====================
__global__ __launch_bounds__(256) void k_tconvb(const float* __restrict__ src,
                                                unsigned short* __restrict__ dst,
                                                int R, int C) {
  src += (size_t)blockIdx.z * R * C;
  dst += (size_t)blockIdx.z * R * C;
  __shared__ float tile[32][33];
  int c0 = blockIdx.x * 32, r0 = blockIdx.y * 32;
  int tx = threadIdx.x & 31, ty = threadIdx.x >> 5;
  #pragma unroll
  for (int i = 0; i < 4; i++) {
    int r = r0 + ty + i*8;
    tile[ty + i*8][tx] = src[(size_t)r*C + c0 + tx];
  }
  __syncthreads();
  #pragma unroll
  for (int i = 0; i < 4; i++) {
    int c = c0 + ty + i*8;
    dst[(size_t)c*R + r0 + tx] = f2b(tile[tx][ty + i*8]);
  }
}

// ===================== MFMA bf16 GEMM: C = alpha * A(M,K) @ B(N,K)^T =====================
// 128 x 128 tile, BK=64, 4 waves (2x2), double-buffered LDS, prefetch-before-compute
// (round-10 schedule: STAGE(next) before compute(cur), one __syncthreads per K-step).
// Staging via global_load_lds width=16 (linear LDS dest + pre-swizzled per-lane source).
// OUT: 0 = f32 store, 1 = bf16 store, 2 = fused swiglu, 3 = indexer IL mode.
// ILV: B row permutation srow = (n>>1) + (n&1)*512 (gate/up interleave)
// MOE: 0 dense; 1 = gather-A by tokp, compact C rows; 2 = compact-A, compact C rows.
// cskip >= 0: skip block if col0 > row0+cskip. ktri: limit K to ceil128(row0+BM).
// nseg>1: segments (A += segA, B += segB). blockIdx.z advances A/B/C by sA/sB/sC.
template<int BM, int OUT, bool ILV, int MOE>
__global__ __launch_bounds__(256) void k_mgemm(
    const unsigned short* __restrict__ A, int lda, long long sA,
    const unsigned short* __restrict__ B, int ldb, long long sB,
    void* __restrict__ Cv, int ldc, long long sC,
    int N, int K, float alpha, int cskip, int ktri,
    int nseg, long long segA, long long segB,
    const float* __restrict__ comb,
    const int* __restrict__ cntp, const int* __restrict__ tokp) {
  constexpr int MR  = BM / 32;     // m-fragments per wave
  constexpr int ITA = BM / 32;     // A staging iterations
  const int row0 = blockIdx.y * BM;
  const int col0 = blockIdx.x * 128;
  const int tid  = threadIdx.x;
  if (cskip >= 0 && col0 > row0 + cskip) {
    if (OUT == 3) {   // NEGR-fill the skipped tile (entirely in causal-masked region)
      float* C = (float*)Cv;
      for (int i = tid; i < BM*32; i += 256) {
        int rr = i >> 5, cc = (i & 31) * 4;
        float4 ng = make_float4(NEGR, NEGR, NEGR, NEGR);
        *(float4*)&C[(size_t)(row0 + rr)*ldc + col0 + cc] = ng;
      }
    }
    return;
  }
  const int zb = blockIdx.z;
  int cnt = 0; long long off = 0;
  if (MOE) {
    cnt = cntp[zb];
    for (int e = 0; e < zb; e++) off += cntp[e];
    if (row0 >= cnt) return;
  }
  __shared__ __align__(16) unsigned short As[2][BM*64];
  __shared__ __align__(16) unsigned short Bs[2][128*64];
  __shared__ float wlds[(OUT == 3) ? BM*32 : 1];
  const int wave = tid >> 6, lane = tid & 63;
  const int wm = wave >> 1, wn = wave & 1;
  A += (size_t)zb * (size_t)sA;
  B += (size_t)zb * (size_t)sB;
  if (MOE == 2) A += off * (long long)lda;

  if constexpr (OUT == 3) {   // stage idxw block: wlds[r*32+h] = idxw[(512+row0+r)*32+h]
    for (int i = tid; i < BM*32; i += 256)
      wlds[i] = comb[(size_t)(row0 + (i >> 5))*32 + (i & 31)];
  }

  int tki[ITA];
  if (MOE == 1) {
    #pragma unroll
    for (int it = 0; it < ITA; it++) {
      int r = (wave*64 + it*256 + lane) >> 3;
      tki[it] = tokp[zb*1024 + row0 + r];   // padded with 0 beyond cnt
    }
  }

  f32x4 acc[MR][4] = {};
  f32x4 acc2[(OUT == 3) ? MR : 1][4] = {};
  const int l15 = lane & 15, l4 = lane >> 4;
  const int sx = l15 & 7;
  int Kend = K;
  if (ktri) {
    int kub = (((row0 + BM - 1) >> 7) + 1) << 7;
    if (kub < Kend) Kend = kub;
  }
  const int nk = Kend >> 6;
  const int nt = nseg * nk;

  auto STAGE = [&](int b, const unsigned short* Ab, const unsigned short* Bb, int k0) {
    #pragma unroll
    for (int it = 0; it < ITA; it++) {
      int base = wave*64 + it*256;        // wave-uniform
      int sidx = base + lane;
      int r = sidx >> 3, s = sidx & 7;
      int s_src = s ^ (r & 7);            // pre-swizzled source slot
      const unsigned short* ga;
      if (MOE == 1) ga = Ab + (size_t)tki[it]*lda + k0 + s_src*8;
      else          ga = Ab + (size_t)(row0 + r)*lda + k0 + s_src*8;
      GLD_LDS16(ga, &As[b][base*8]);
    }
    #pragma unroll
    for (int it = 0; it < 4; it++) {
      int base = wave*64 + it*256;
      int sidx = base + lane;
      int r = sidx >> 3, s = sidx & 7;
      int s_src = s ^ (r & 7);
      int rt = col0 + r;
      int srow = ILV ? ((rt >> 1) + (rt & 1)*512) : rt;
      const unsigned short* gb = Bb + (size_t)srow*ldb + k0 + s_src*8;
      GLD_LDS16(gb, &Bs[b][base*8]);
    }
  };

  // prologue: stage tile 0
  STAGE(0, A, B, 0);
  int ks = 64, sg = 0;
  if (ks == Kend) { ks = 0; sg = 1; }
  __syncthreads();                         // drains vmcnt -> tile 0 resident (+ wlds visible)
  int cur = 0;

  for (int u = 0; u < nt; u++) {
    if (u + 1 < nt) {
      STAGE(cur ^ 1, A + (size_t)sg*segA, B + (size_t)sg*segB, ks);
      ks += 64;
      if (ks == Kend) { ks = 0; sg++; }
    }
    #pragma unroll
    for (int kc = 0; kc < 2; kc++) {
      const int sl = ((kc*4 + l4) ^ sx) << 3;
      bf16x8 fa[MR], fb[4];
      #pragma unroll
      for (int mf = 0; mf < MR; mf++)
        fa[mf] = *(const bf16x8*)&As[cur][(wm*(BM/2) + mf*16 + l15)*64 + sl];
      #pragma unroll
      for (int nf = 0; nf < 4; nf++)
        fb[nf] = *(const bf16x8*)&Bs[cur][(wn*64 + nf*16 + l15)*64 + sl];
      #pragma unroll
      for (int mf = 0; mf < MR; mf++)
        #pragma unroll
        for (int nf = 0; nf < 4; nf++)
          acc[mf][nf] = __builtin_amdgcn_mfma_f32_16x16x32_bf16(fa[mf], fb[nf], acc[mf][nf], 0, 0, 0);
    }
    if constexpr (OUT == 3) {   // end-of-segment fold: acc2 += relu(acc)*w[t,h]; acc = 0
      if ((u + 1) % nk == 0) {
        int h = u / nk;
        #pragma unroll
        for (int mf = 0; mf < MR; mf++) {
          #pragma unroll
          for (int r = 0; r < 4; r++) {
            int rl = wm*(BM/2) + mf*16 + l4*4 + r;
            float w = wlds[rl*32 + h];
            #pragma unroll
            for (int nf = 0; nf < 4; nf++) {
              acc2[mf][nf][r] += fmaxf(acc[mf][nf][r], 0.f) * w;
              acc[mf][nf][r] = 0.f;
            }
          }
        }
      }
    }
    __syncthreads();                       // drains vmcnt -> next tile resident
    cur ^= 1;
  }

  // C write: col = lane&15, row = (lane>>4)*4 + reg  [m89-verified]
  #pragma unroll
  for (int mf = 0; mf < MR; mf++) {
    #pragma unroll
    for (int nf = 0; nf < 4; nf++) {
      int n = col0 + wn*64 + nf*16 + l15;
      #pragma unroll
      for (int r = 0; r < 4; r++) {
        int m = row0 + wm*(BM/2) + mf*16 + l4*4 + r;
        if (OUT == 3) {
          float v = acc2[mf][nf][r];
          if (n > 512 + m) v = NEGR;       // causal mask (t = 512 + m)
          ((float*)Cv)[(size_t)m*ldc + n] = v;
          continue;
        }
        float v = acc[mf][nf][r] * alpha;
        if (OUT == 2) {
          float p = __shfl_xor(v, 1, 64);     // pair lane exchange (g,u)
          if ((l15 & 1) == 0) {
            bool ok = true;
            long long mrow = m;
            float w;
            if (MOE == 1) {
              ok = (m < cnt); mrow = off + m;
              int tok = tokp[zb*1024 + m];
              w = (zb < 8) ? comb[tok*8 + zb] : 1.f;
            } else {
              w = (zb < 8) ? comb[m*8 + zb] : 1.f;
            }
            if (ok) {
              float rres = v/(1.f + expf(-v)) * p * w;
              ((unsigned short*)Cv)[(size_t)zb*sC + (size_t)mrow*ldc + (n >> 1)] = f2b(rres);
            }
          }
        } else if (n < N) {
          bool ok = true;
          long long mrow = m;
          if (MOE == 2) { ok = (m < cnt); mrow = off + m; }
          if (ok) {
            size_t idx = (size_t)mrow*ldc + n;
            if (OUT == 1) ((unsigned short*)Cv)[(size_t)zb*sC + idx] = f2b(v);
            else          ((float*)Cv)[(size_t)zb*sC + idx] = v;
          }
        }
      }
    }
  }
}

// ===================== post-s1 (sums 2 split-K partials; writes KVB/IDXKB bf16 directly) =====================
__global__ __launch_bounds__(256) void k_post1(const float* __restrict__ s1a,
    const float* __restrict__ s1b,
    const float* __restrict__ wq, const float* __restrict__ wkv,
    const float* __restrict__ lnw, const float* __restrict__ lnb,
    const float* __restrict__ cosb, const float* __restrict__ sinb,
    unsigned short* __restrict__ qcb, float* __restrict__ kvc,
    unsigned short* __restrict__ kvb, unsigned short* __restrict__ idxkb,
    float* __restrict__ idxw) {
  int t = blockIdx.x, tid = threadIdx.x;
  __shared__ float rowb[S1W];
  __shared__ float scr[4];
  __shared__ float yb[128];
  for (int d = tid; d < S1W; d += 256)
    rowb[d] = s1a[(size_t)t*S1W + d] + s1b[(size_t)t*S1W + d];
  __syncthreads();
  float ss = 0.f;
  for (int d = tid; d < QL; d += 256) { float v = rowb[d]; ss = fmaf(v,v,ss); }
  ss = blk_sum256(ss, scr);
  float inv = 1.f/sqrtf(ss/(float)QL + 1e-6f);
  for (int d = tid; d < QL; d += 256) qcb[(size_t)t*QL + d] = f2b(rowb[d]*inv*wq[d]);
  ss = 0.f;
  for (int d = tid; d < KVL; d += 256) { float v = rowb[QL+d]; ss = fmaf(v,v,ss); }
  ss = blk_sum256(ss, scr);
  inv = 1.f/sqrtf(ss/(float)KVL + 1e-6f);
  for (int d = tid; d < KVL; d += 256) {
    float v = rowb[QL+d]*inv*wkv[d];
    kvc[(size_t)t*KVL + d] = v;
    kvb[(size_t)t*576 + d] = f2b(v);
  }
  float sm = (tid < 128) ? rowb[1344 + tid] : 0.f;
  float tot = blk_sum256(sm, scr);
  float mean = tot / 128.f;
  float vs = 0.f;
  if (tid < 128) { float v = rowb[1344+tid] - mean; vs = v*v; }
  vs = blk_sum256(vs, scr);
  float ivn = 1.f/sqrtf(vs/128.f + 1e-6f);
  if (tid < 128) yb[tid] = (rowb[1344+tid]-mean)*ivn*lnw[tid] + lnb[tid];
  __syncthreads();
  if (tid < 32) {
    float c = cosb[t*32 + tid], s = sinb[t*32 + tid];
    idxkb[(size_t)t*ID + tid]      = f2b(yb[tid]*c - yb[32+tid]*s);
    idxkb[(size_t)t*ID + 32 + tid] = f2b(yb[32+tid]*c + yb[tid]*s);
    float x1 = rowb[1280+tid], x2 = rowb[1312+tid];
    kvb[(size_t)t*576 + 512 + tid] = f2b(x1*c - x2*s);
    kvb[(size_t)t*576 + 544 + tid] = f2b(x2*c + x1*s);
    idxw[(size_t)t*IH + tid] = rowb[1472+tid] * SC_IDXW;
  } else if (tid >= 64 && tid < 128) {
    idxkb[(size_t)t*ID + tid] = f2b(yb[tid]);
  }
}

// ===================== post-s3: rope/scale in LDS; writes S3B bf16 + QMQAB pe cols =====================
__global__ __launch_bounds__(256) void k_post3b(const float* __restrict__ s3,
                                                const float* __restrict__ cosb,
                                                const float* __restrict__ sinb,
                                                unsigned short* __restrict__ s3b,
                                                unsigned short* __restrict__ qm) {
  int t = blockIdx.x, tid = threadIdx.x;
  const float* row = s3 + (size_t)t*S3W;
  __shared__ float buf[S3W];
  __shared__ float cs[32], sn[32];
  if (tid < 32) { cs[tid] = cosb[t*32+tid]; sn[tid] = sinb[t*32+tid]; }
  for (int d = tid; d < S3W; d += 256) buf[d] = row[d];
  __syncthreads();
  for (int p = tid; p < 1024; p += 256) {
    int h = p >> 5, d = p & 31;
    float c = cs[d], s = sn[d];
    float x1 = buf[h*ID + d], x2 = buf[h*ID + 32 + d];
    buf[h*ID + d]      = (x1*c - x2*s) * SC_IDXQ;
    buf[h*ID + 32 + d] = (x2*c + x1*s) * SC_IDXQ;
  }
  for (int p = tid; p < 2048; p += 256) {
    int h = p >> 6, d = 64 + (p & 63);
    buf[h*ID + d] *= SC_IDXQ;
  }
  for (int p = tid; p < 512; p += 256) {
    int h = p >> 5, d = p & 31;
    float c = cs[d], s = sn[d];
    int base = IH*ID + h*192 + 128;
    float x1 = buf[base + d], x2 = buf[base + 32 + d];
    float r1 = x1*c - x2*s, r2 = x2*c + x1*s;
    buf[base + d]      = r1;
    buf[base + 32 + d] = r2;
    qm[(size_t)t*9216 + h*576 + 512 + d] = f2b(r1 * SCALE_ATT);
    qm[(size_t)t*9216 + h*576 + 544 + d] = f2b(r2 * SCALE_ATT);
  }
  __syncthreads();
  unsigned short* orow = s3b + (size_t)t*S3W;
  for (int g = tid*4; g < S3W; g += 1024) {
    ushort4 o;
    o.x = f2b(buf[g]); o.y = f2b(buf[g+1]); o.z = f2b(buf[g+2]); o.w = f2b(buf[g+3]);
    *(ushort4*)(orow + g) = o;
  }
}

// ===================== exact per-row top-512 (bitonic, tie -> lower index) =====================
__global__ __launch_bounds__(512) void k_topk(const float* __restrict__ isc,
                                              unsigned char* __restrict__ mask) {
  int t = 512 + blockIdx.x;
  const float* row = isc + (size_t)blockIdx.x * TT;
  __shared__ unsigned long long keys[1024];
  int tid = threadIdx.x;
  for (int i = tid; i < 1024; i += 512) {
    float v = row[i];
    unsigned int b = __float_as_uint(v);
    unsigned int u = (b & 0x80000000u) ? ~b : (b | 0x80000000u);
    keys[i] = ((unsigned long long)u << 32) | (unsigned int)(1023 - i);
  }
  __syncthreads();
  for (int k = 2; k <= 1024; k <<= 1) {
    for (int j = k >> 1; j > 0; j >>= 1) {
      int i = ((tid & ~(j - 1)) << 1) | (tid & (j - 1));
      int l = i | j;
      unsigned long long a = keys[i], b = keys[l];
      bool up = ((i & k) == 0);
      if ((a < b) == up) { keys[i] = b; keys[l] = a; }
      __syncthreads();
    }
  }
  unsigned char* mrow = mask + (size_t)t * TT;
  for (int p = tid; p < 1024; p += 512) {
    int s = 1023 - (int)(keys[p] & 0xFFFFFFFFu);
    mrow[s] = (p < 512) ? (unsigned char)1 : (unsigned char)0;
  }
}

// ===================== masked softmax over P rows (in place, bf16; width-limited) =====================
__global__ __launch_bounds__(256) void k_psoft(unsigned short* __restrict__ pb,
                                               const unsigned char* __restrict__ mask) {
  int b = blockIdx.x;
  int t = b & 1023, h = b >> 10;
  unsigned short* row = pb + ((size_t)h << 20) + ((size_t)t << 10);
  int tid = threadIdx.x;
  __shared__ float scr[4];
  int s0 = tid * 4;
  int rub = ((t >> 7) + 1) << 7;       // PV (ktri) reads cols < rub only
  bool act = (s0 < rub);
  float v0 = 0.f, v1 = 0.f, v2 = 0.f, v3 = 0.f;
  bool m0 = false, m1 = false, m2 = false, m3 = false;
  if (act) {
    ushort4 raw = *(const ushort4*)(row + s0);
    v0 = b2f(raw.x); v1 = b2f(raw.y); v2 = b2f(raw.z); v3 = b2f(raw.w);
    if (t < 512) {
      m0 = (s0 <= t); m1 = (s0+1 <= t); m2 = (s0+2 <= t); m3 = (s0+3 <= t);
    } else {
      uchar4 mk = *(const uchar4*)(mask + (size_t)t*TT + s0);
      m0 = (s0 <= t) && mk.x; m1 = (s0+1 <= t) && mk.y;
      m2 = (s0+2 <= t) && mk.z; m3 = (s0+3 <= t) && mk.w;
    }
  }
  float mx = NEGL;
  if (m0) mx = v0;
  if (m1) mx = fmaxf(mx, v1);
  if (m2) mx = fmaxf(mx, v2);
  if (m3) mx = fmaxf(mx, v3);
  #pragma unroll
  for (int o = 32; o > 0; o >>= 1) mx = fmaxf(mx, __shfl_down(mx, o, 64));
  __syncthreads();
  if ((tid & 63) == 0) scr[tid >> 6] = mx;
  __syncthreads();
  mx = fmaxf(fmaxf(scr[0], scr[1]), fmaxf(scr[2], scr[3]));
  float p0 = m0 ? expf(v0 - mx) : 0.f;
  float p1 = m1 ? expf(v1 - mx) : 0.f;
  float p2 = m2 ? expf(v2 - mx) : 0.f;
  float p3 = m3 ? expf(v3 - mx) : 0.f;
  float sum = blk_sum256((p0+p1)+(p2+p3), scr);
  float inv = 1.f / sum;
  if (act) {
    ushort4 o;
    o.x = f2b(p0*inv); o.y = f2b(p1*inv); o.z = f2b(p2*inv); o.w = f2b(p3*inv);
    *(ushort4*)(row + s0) = o;
  }
}

// ===================== routing compaction: per-expert stable token lists =====================
__global__ __launch_bounds__(1024) void k_route(const float* __restrict__ comb,
                                                int* __restrict__ tokidx,
                                                int* __restrict__ rank,
                                                int* __restrict__ cntp) {
  int e = blockIdx.x;   // 0..8 (8 = shared identity)
  int t = threadIdx.x;  // 0..1023
  if (e == 8) {
    tokidx[8*1024 + t] = t;
    if (t == 0) cntp[8] = 1024;
    return;
  }
  int lane = t & 63, w = t >> 6;
  bool sel = comb[t*8 + e] != 0.0f;
  unsigned long long bal = __ballot(sel);
  int pw = __popcll(bal & ((1ull << lane) - 1ull));
  int wt = __popcll(bal);
  __shared__ int wsum[16];
  if (lane == 0) wsum[w] = wt;
  __syncthreads();
  int woff = 0, total = 0;
  #pragma unroll
  for (int i = 0; i < 16; i++) { int v = wsum[i]; if (i < w) woff += v; total += v; }
  int pos = woff + pw;
  rank[t*8 + e] = sel ? pos : -1;
  if (sel) tokidx[e*1024 + pos] = t;
  __syncthreads();
  if (t >= total) tokidx[e*1024 + t] = 0;  // pad
  if (t == 0) cntp[e] = total;
}

// ===================== gather-sum: out[t] = shared + sum_e selected expert rows (bf16 DPC) =====================
__global__ __launch_bounds__(256) void k_rsum(const unsigned short* __restrict__ dpc,
                                              const int* __restrict__ rank,
                                              const int* __restrict__ cntp,
                                              float* __restrict__ out) {
  int t = blockIdx.x;
  int d = threadIdx.x * 8;
  int offs[8]; int acc_off = 0;
  #pragma unroll
  for (int e = 0; e < 8; e++) { offs[e] = acc_off; acc_off += cntp[e]; }
  const unsigned short* ps = dpc + (size_t)(acc_off + t)*2048 + d;   // shared row
  ushort4 u0 = *(const ushort4*)ps;
  ushort4 u1 = *(const ushort4*)(ps + 4);
  float a[8];
  a[0]=b2f(u0.x); a[1]=b2f(u0.y); a[2]=b2f(u0.z); a[3]=b2f(u0.w);
  a[4]=b2f(u1.x); a[5]=b2f(u1.y); a[6]=b2f(u1.z); a[7]=b2f(u1.w);
  #pragma unroll
  for (int e = 0; e < 8; e++) {
    int r = rank[t*8 + e];
    if (r >= 0) {
      const unsigned short* p = dpc + (size_t)(offs[e] + r)*2048 + d;
      ushort4 b0 = *(const ushort4*)p;
      ushort4 b1 = *(const ushort4*)(p + 4);
      a[0]+=b2f(b0.x); a[1]+=b2f(b0.y); a[2]+=b2f(b0.z); a[3]+=b2f(b0.w);
      a[4]+=b2f(b1.x); a[5]+=b2f(b1.y); a[6]+=b2f(b1.z); a[7]+=b2f(b1.w);
    }
  }
  float* po = out + (size_t)t*2048 + d;
  *(float4*)po       = make_float4(a[0], a[1], a[2], a[3]);
  *(float4*)(po + 4) = make_float4(a[4], a[5], a[6], a[7]);
}

// ===================== launch =====================
extern "C" void kernel_launch(void* const* d_in, const int* in_sizes, int n_in,
                              void* d_out, int out_size, void* d_ws, size_t ws_size,
                              hipStream_t stream) {
  const int*   positions = (const int*)d_in[0];
  const float* hs     = (const float*)d_in[1];
  const float* rsd    = (const float*)d_in[2];
  const float* w_in   = (const float*)d_in[3];
  const float* w_post = (const float*)d_in[4];
  const float* w_s1   = (const float*)d_in[5];
  const float* w_qln  = (const float*)d_in[6];
  const float* w_kvln = (const float*)d_in[7];
  const float* iklnw  = (const float*)d_in[8];
  const float* iklnb  = (const float*)d_in[9];
  const float* w_s3   = (const float*)d_in[10];
  const float* wukt   = (const float*)d_in[11];
  const float* wuv    = (const float*)d_in[12];
  const float* w_o    = (const float*)d_in[13];
  const float* gate_w = (const float*)d_in[14];
  const float* gate_b = (const float*)d_in[15];
  const float* sh_gu  = (const float*)d_in[16];
  const float* sh_dn  = (const float*)d_in[17];
  const float* ex_gu  = (const float*)d_in[18];
  const float* ex_dn  = (const float*)d_in[19];

  float* ws = (float*)d_ws;
  typedef unsigned short ush;
  // -------- workspace layout (float units), phase-disjoint aliasing; peak 34,152,448 f = 136.6 MB --------
  // persistent
  float* RES   = ws + 0;          // 2,097,152
  float* COSB  = ws + 2097152;    // 32,768
  float* SINB  = ws + 2129920;    // 32,768
  float* KVC   = ws + 2162688;    // 524,288
  float* IDXW  = ws + 2883584;    // 32,768
  float* COMB  = ws + 2916352;    // 8,192
  // phase A
  ush*   HB    = (ush*)(ws + 2924544);   // 2,097,152 ush -> ends f 3,973,120
  ush*   WS1B  = (ush*)(ws + 3973120);   // 3,145,728 ush (1536x2048 padded) -> ends f 5,545,984
  float* S1P0  = ws + 5545984;           // 1,540,096 -> ends 7,086,080
  ush*   QCB   = (ush*)(ws + 7086080);   // 786,432 ush -> ends f 7,479,296
  ush*   WS3B  = (ush*)(ws + 7479296);   // 5,505,024 ush -> ends f 10,231,808
  float* S3    = ws + 10231808;          // 7,340,032 f32 -> ends 17,571,840
  float* S1P1  = ws + 10231808;          // 1,540,096 (split-K partial 1; dead before S3 write)
  ush*   S3B   = (ush*)(ws + 17571840);  // 7,340,032 ush -> ends f 21,241,856
  ush*   WUKTB = (ush*)(ws + 21241856);  // 1,048,576 ush -> ends f 21,766,144
  ush*   QMQAB = (ush*)(ws + 21766144);  // 9,437,184 ush : [t][h][576] -> ends f 26,484,736
  float* ISC   = ws + 26484736;          // 524,288 -> ends 27,009,024
  unsigned char* MASK = (unsigned char*)(ws + 27009024); // 1,048,576 B -> ends f 27,271,168
  ush*   WUVB  = (ush*)(ws + 27271168);  // 1,048,576 ush -> ends f 27,795,456
  ush*   KVB   = (ush*)(ws + 27795456);  // 589,824 ush -> ends f 28,090,368
  ush*   VTB   = (ush*)(ws + 28090368);  // 524,288 ush : V^T (512,1024) -> ends f 28,352,512
  ush*   O2B   = (ush*)(ws + 28352512);  // 2,097,152 ush -> ends f 29,401,088
  ush*   IDXKB = (ush*)(ws + 31989760);  // 131,072 ush -> ends f 32,055,296
  ush*   WOB   = (ush*)(ws + 32055296);  // 4,194,304 ush (w_o bf16; own region) -> ends f 34,152,448
  ush*   PB    = (ush*)(ws + 10231808);  // 16,777,216 ush : [h][t][1024] (overlays dead S3/S3B head)
  ush*   OHB   = (ush*)(ws + 18620416);  // 8,388,608 ush : [h][t][512] (overlays dead S3B tail/WUKTB/QMQAB head)
  float* ATTNP = ws + 10231808;          // 2 x 2,097,152 (split-K partials; overlays dead PB)
  // phase B (all written after k_res2g)
  ush*   H2B    = (ush*)(ws + 5021696);  // 2,097,152 ush -> ends f 6,070,272
  ush*   EXGUB  = (ush*)(ws + 6070272);  // 16,777,216 ush -> ends f 14,458,880
  ush*   SHGUB  = (ush*)(ws + 14458880); // 2,097,152 ush (contiguous after EXGUB => z=8)
  ush*   EXDNB  = (ush*)(ws + 15507456); // 8,388,608 ush -> ends f 19,701,760
  ush*   SHDNB  = (ush*)(ws + 19701760); // 1,048,576 ush (contiguous => expert 8)
  ush*   ACTC   = (ush*)(ws + 20226048); // 5120x512 ush compacted acts -> ends f 21,536,768
  ush*   DPC    = (ush*)(ws + 21536768); // 5120x2048 ush compacted down outputs -> ends f 26,779,648
  int*   TOKIDX = (int*)(ws + 32022528); // 9x1024 int (phase-B; overlays dead IDXKB tail)
  int*   RANK   = (int*)(ws + 32031744); // 1024x8 int
  int*   CNT    = (int*)(ws + 32039936); // 16 int

  float* OUT0 = (float*)d_out;
  float* OUT_RES2 = OUT0 + (size_t)TT*HID;

  // 1. prelude (+ fused rope tables)
  k_prelude<<<TT, 256, 0, stream>>>(hs, rsd, w_in, positions, RES, HB, COSB, SINB);
  // 2. early weight conversions: w_s1 (padded), then w_s3|w_o fused, transposed wukt/wuv
  k_f2b<<<1024, 256, 0, stream>>>(w_s1, WS1B, 3080192LL, 3145728LL);
  k_f2b4<<<2048, 256, 0, stream>>>(w_s3, WS3B, 5505024LL,
                                   w_o,  WOB,  4194304LL,
                                   w_s3, WS3B, 0LL,
                                   w_s3, WS3B, 0LL);
  k_tconvb<<<dim3(16,4,16), 256, 0, stream>>>(wukt, WUKTB, 128, 512);
  k_tconvb<<<dim3(4,16,16), 256, 0, stream>>>(wuv, WUVB, 512, 128);
  // 3. s1 = h @ w_s1^T, split-K z=2 (K halves of 1024) -> partials
  k_mgemm<128,0,false,0><<<dim3(12,8,2), 256, 0, stream>>>(
      HB, 2048, 1024, WS1B, 2048, 1024, S1P0, S1W, 4685824,
      1504, 1024, 1.f, -1, 0, 1, 0, 0, nullptr, nullptr, nullptr);
  // 4. post-s1 (sums partials); writes QCB, KVC f32, KVB bf16 concat, IDXKB bf16, IDXW
  k_post1<<<TT, 256, 0, stream>>>(S1P0, S1P1, w_qln, w_kvln, iklnw, iklnb, COSB, SINB,
                                  QCB, KVC, KVB, IDXKB, IDXW);
  // 5. s3 = q_c @ w_s3^T
  k_mgemm<128,0,false,0><<<dim3(56,8,1), 256, 0, stream>>>(
      QCB, 768, 0, WS3B, 768, 0, S3, S3W, 0,
      S3W, 768, 1.f, -1, 0, 1, 0, 0, nullptr, nullptr, nullptr);
  // 6. post-s3: rope/scale + bf16 write + QMQAB pe cols fused
  k_post3b<<<TT, 256, 0, stream>>>(S3, COSB, SINB, (ush*)S3B, QMQAB);
  // 7. ql_nope -> QMQAB[:, :, 0:512] (SCALE_ATT folded)
  k_mgemm<128,1,false,0><<<dim3(4,8,16), 256, 0, stream>>>(
      S3B + 4096, S3W, 192, WUKTB, 128, 65536, QMQAB, 9216, 576,
      512, 128, SCALE_ATT, -1, 0, 1, 0, 0, nullptr, nullptr, nullptr);
  // 8. indexer scores: fused 32 head-segments, relu-weighted fold -> ISC (causal NEGR)
  k_mgemm<64,3,false,0><<<dim3(8,8,1), 256, 0, stream>>>(
      S3B + (size_t)512*S3W, S3W, 0, IDXKB, 128, 0,
      ISC, 1024, 0, 1024, 128, 1.f, 575, 0, 32, 128, 0,
      IDXW + (size_t)512*IH, nullptr, nullptr);
  // 9. exact top-512
  k_topk<<<512, 512, 0, stream>>>(ISC, MASK);
  // 10. V^T bf16
  k_tconvb<<<dim3(16,32,1), 256, 0, stream>>>(KVC, VTB, 1024, 512);
  // 11. logits P = Qmqa @ KV^T (per head), causal block-skip -> bf16
  k_mgemm<128,1,false,0><<<dim3(8,8,16), 256, 0, stream>>>(
      QMQAB, 9216, 576, KVB, 576, 0, PB, 1024, 1048576,
      1024, 576, 1.f, 127, 0, 1, 0, 0, nullptr, nullptr, nullptr);
  // 12. masked softmax in place (zeros masked entries up to the 128-block bound)
  k_psoft<<<16384, 256, 0, stream>>>(PB, MASK);
  // 13. O = P @ V (per head), K truncated to causal bound (ktri) -> OHB bf16
  k_mgemm<128,1,false,0><<<dim3(4,8,16), 256, 0, stream>>>(
      PB, 1024, 1048576, VTB, 1024, 0, OHB, 512, 524288,
      512, 1024, 1.f, -1, 1, 1, 0, 0, nullptr, nullptr, nullptr);
  // 14. o2 = O @ W_UV (per head) -> O2B [t][h*128]
  k_mgemm<128,1,false,0><<<dim3(1,8,16), 256, 0, stream>>>(
      OHB, 512, 524288, WUVB, 512, 65536, O2B, 2048, 128,
      128, 512, 1.f, -1, 0, 1, 0, 0, nullptr, nullptr, nullptr);
  // 15. attn_out = o2 @ w_o^T, split-K z=2 -> partials
  k_mgemm<128,0,false,0><<<dim3(16,8,2), 256, 0, stream>>>(
      O2B, 2048, 1024, WOB, 2048, 1024, ATTNP, 2048, 2097152,
      2048, 1024, 1.f, -1, 0, 1, 0, 0, nullptr, nullptr, nullptr);
  // 16. res2 (sums partials) + h2 bf16 + fused routing -> COMB
  k_res2g<<<TT, 256, 0, stream>>>(ATTNP, ATTNP + 2097152, RES, w_post, gate_w, gate_b,
                                  OUT_RES2, H2B, COMB);
  // 17. deterministic compaction
  k_route<<<9, 1024, 0, stream>>>(COMB, TOKIDX, RANK, CNT);
  // 18. fused late weight conversions (ex_gu | sh_gu | ex_dn | sh_dn)
  k_f2b4<<<2048, 256, 0, stream>>>(ex_gu, EXGUB, 16777216LL,
                                   sh_gu, SHGUB, 2097152LL,
                                   ex_dn, EXDNB, 8388608LL,
                                   sh_dn, SHDNB, 1048576LL);
  // 19. sparse gate-up (9 experts incl shared), A gathered by TOKIDX, swiglu+comb fused
  k_mgemm<128,2,true,1><<<dim3(8,8,9), 256, 0, stream>>>(
      H2B, 2048, 0, EXGUB, 2048, 2097152, ACTC, 512, 0,
      1024, 2048, 1.f, -1, 0, 1, 0, 0, COMB, CNT, TOKIDX);
  // 20. sparse down-proj per expert: DPC[off_e + i][2048] bf16
  k_mgemm<128,1,false,2><<<dim3(16,8,9), 256, 0, stream>>>(
      ACTC, 512, 0, EXDNB, 512, 1048576, DPC, 2048, 0,
      2048, 512, 1.f, -1, 0, 1, 0, 0, nullptr, CNT, nullptr);
  // 21. out[t] = shared + sum of t's selected expert rows (fixed ascending-e order)
  k_rsum<<<TT, 256, 0, stream>>>(DPC, RANK, CNT, OUT0);
}